// Round 15
// baseline (171.817 us; speedup 1.0000x reference)
//
#include <hip/hip_runtime.h>
#include <hip/hip_bf16.h>

typedef __attribute__((ext_vector_type(8))) short bf16x8;
typedef __attribute__((ext_vector_type(4))) float f32x4;
typedef float f32x4u __attribute__((ext_vector_type(4), aligned(4)));  // dword-aligned vec4
typedef __attribute__((ext_vector_type(4))) unsigned int uint32x4;

#define N_TOK 1024
#define HEADS 8
#define DIM_HEAD 64
#define BATCH 8
#define DIMM 512
#define INNER 512
#define QKV_COLS 1536

#define MFMA16 __builtin_amdgcn_mfma_f32_16x16x32_bf16

__device__ inline short f2bf(float f) {
  union { float f; unsigned u; } v;
  v.f = f;
  unsigned r = v.u + 0x7fffu + ((v.u >> 16) & 1u);  // RNE
  return (short)(r >> 16);
}

__device__ inline unsigned pack2bf(float a, float b) {
  return ((unsigned)(unsigned short)f2bf(a)) | (((unsigned)(unsigned short)f2bf(b)) << 16);
}

// LDS-only barrier: orders LDS across waves WITHOUT draining global stores
__device__ inline void lds_barrier() {
  asm volatile("s_waitcnt lgkmcnt(0)" ::: "memory");
  __builtin_amdgcn_s_barrier();
  asm volatile("" ::: "memory");
}

// direct global->LDS 16B/lane (dest = wave-uniform base + lane*16)
__device__ inline void gload_lds16(const short* g, short* l) {
  __builtin_amdgcn_global_load_lds(
      (const __attribute__((address_space(1))) void*)g,
      (__attribute__((address_space(3))) void*)l, 16, 0, 0);
}

// ---------------- merged prep: x->bf16 | Wqkv^T | Wout^T | bias2e ----------------
__global__ __launch_bounds__(256)
void prep_kernel(const float* __restrict__ x, short* __restrict__ xb,
                 const float* __restrict__ Wqkv, short* __restrict__ WqT,
                 const float* __restrict__ Wout, short* __restrict__ WoT,
                 const float* __restrict__ rel, const float* __restrict__ headsita,
                 float* __restrict__ bias2e) {
  const int blk = blockIdx.x, t = threadIdx.x;
  if (blk < 4096) {                      // x fp32 -> bf16 (4M elems, x4/thread)
    int i = (blk * 256 + t) * 4;
    float4 v = *(const float4*)&x[i];
    short4 o;
    o.x = f2bf(v.x); o.y = f2bf(v.y); o.z = f2bf(v.z); o.w = f2bf(v.w);
    *(short4*)&xb[i] = o;
  } else if (blk < 7168) {               // Wqkv [512][1536] -> WqT [1536][512]
    int id = (blk - 4096) * 256 + t;
    int n = id % 1536, k = id / 1536;
    WqT[n * 512 + k] = f2bf(Wqkv[id]);
  } else if (blk < 8192) {               // Wout [512][512] -> WoT [512][512]
    int id = (blk - 7168) * 256 + t;
    int n = id & 511, k = id >> 9;
    WoT[n * 512 + k] = f2bf(Wout[id]);
  } else {                               // bias2e [8][4096]
    int e = (blk - 8192) * 256 + t;
    int h = e >> 12, idx = e & 4095;
    if (idx >= 3969) return;
    int dr = idx / 63 - 31;
    int dc = idx % 63 - 31;
    float th = headsita[h];
    float factor = 1.f / (2.f * th * th + 1e-10f);
    float dis = (float)(dr * dr + dc * dc) * (1.0f / 1024.0f);
    bias2e[e] = __expf(rel[idx * HEADS + h] + 0.01f * __expf(-factor * dis));
  }
}

// ---------------- bf16 MFMA GEMM, m97-style staging ----------------
template<int SPLIT>
__global__ __launch_bounds__(256)
void gemm_kernel(const short* __restrict__ A, const short* __restrict__ Bt,
                 void* __restrict__ C, const float* __restrict__ bias,
                 short* __restrict__ Qb, short* __restrict__ Kfrag,
                 short* __restrict__ Vfrag,
                 int M, int Nc, int K, int lda)
{
  __shared__ short Ash[128 * 32];   // linear row-major [128][32] (gload_lds dest)
  __shared__ short Bsh[128 * 32];
  const int t = threadIdx.x;
  const int lane = t & 63, wave = t >> 6;
  const int wm = wave >> 1, wn = wave & 1;
  const int m0 = blockIdx.y * 128, n0 = blockIdx.x * 128;
  const int grow = wave * 32 + (lane >> 2);
  const int gcol = (lane & 3) * 8;
  f32x4 acc[4][4] = {};
  for (int k0 = 0; k0 < K; k0 += 32) {
    lds_barrier();
    #pragma unroll
    for (int i = 0; i < 2; ++i) {
      gload_lds16(&A[(size_t)(m0 + grow + i * 16) * lda + k0 + gcol],
                  &Ash[(wave * 32 + i * 16) * 32]);
      gload_lds16(&Bt[(size_t)(n0 + grow + i * 16) * K + k0 + gcol],
                  &Bsh[(wave * 32 + i * 16) * 32]);
    }
    asm volatile("s_waitcnt vmcnt(0)" ::: "memory");
    __builtin_amdgcn_s_barrier();
    asm volatile("" ::: "memory");
    bf16x8 af[4], bfr[4];
    #pragma unroll
    for (int m = 0; m < 4; ++m)
      af[m] = *(const bf16x8*)&Ash[(wm * 64 + m * 16 + (lane & 15)) * 32 + (lane >> 4) * 8];
    #pragma unroll
    for (int n = 0; n < 4; ++n)
      bfr[n] = *(const bf16x8*)&Bsh[(wn * 64 + n * 16 + (lane & 15)) * 32 + (lane >> 4) * 8];
    #pragma unroll
    for (int m = 0; m < 4; ++m)
      #pragma unroll
      for (int n = 0; n < 4; ++n)
        acc[m][n] = MFMA16(af[m], bfr[n], acc[m][n], 0, 0, 0);
  }
  const int r0 = (lane >> 4) * 4, c0 = lane & 15;
  if (!SPLIT) {
    #pragma unroll
    for (int m = 0; m < 4; ++m)
      #pragma unroll
      for (int n = 0; n < 4; ++n) {
        int col = n0 + wn*64 + n*16 + c0;
        float bv = bias[col];
        #pragma unroll
        for (int r = 0; r < 4; ++r) {
          int row = m0 + wm*64 + m*16 + r0 + r;
          ((float*)C)[(size_t)row * Nc + col] = acc[m][n][r] + bv;
        }
      }
  } else {
    const int seg = n0 >> 9;   // 0=Q, 1=K, 2=V (each 512 cols = 4 blocks)
    #pragma unroll
    for (int m = 0; m < 4; ++m)
      #pragma unroll
      for (int n = 0; n < 4; ++n) {
        const int colg = n0 + wn*64 + n*16 + c0;
        const int rowg0 = m0 + wm*64 + m*16 + r0;
        if (seg == 0) {
          #pragma unroll
          for (int rr = 0; rr < 4; ++rr)
            Qb[(size_t)(rowg0 + rr) * 512 + colg] = f2bf(acc[m][n][rr]);
        } else if (seg == 1) {
          const int d = colg - 512, h = d >> 6, dd = d & 63;
          const int b = rowg0 >> 10, j0 = rowg0 & 1023;
          const size_t base = ((((size_t)(b * 8 + h) * 16 + (j0 >> 6)) * 8)
                               + ((j0 >> 4) & 3) * 2 + (dd >> 5)) * 512
                              + ((dd >> 3) & 3) * 128 + (dd & 7);
          #pragma unroll
          for (int rr = 0; rr < 4; ++rr)
            Kfrag[base + ((j0 + rr) & 15) * 8] = f2bf(acc[m][n][rr]);
        } else {
          const int d = colg - 1024, h = d >> 6, dd = d & 63;
          const int b = rowg0 >> 10, j0 = rowg0 & 1023;
          const int w = j0 >> 7, j7 = j0 & 127;
          const int rgv = (((j7 >> 6) & 1) << 1) | ((j7 >> 3) & 1);
          const int wvv = (j7 >> 4) & 3, e0 = j7 & 7;   // e0 in {0,4}
          const size_t addr = (((size_t)(b * 8 + h) * 8 + w) * 16 + wvv * 4 + (dd >> 4)) * 512
                              + (rgv * 16 + (dd & 15)) * 8 + e0;
          short4 sv;
          sv.x = f2bf(acc[m][n][0]); sv.y = f2bf(acc[m][n][1]);
          sv.z = f2bf(acc[m][n][2]); sv.w = f2bf(acc[m][n][3]);
          *(short4*)&Vfrag[addr] = sv;
        }
      }
  }
}

// ---------------- fused attention v15: fused (s0,s1) reduce + setprio + 4 barriers ----------------
// Bias gathered DURING the exp pass (loads overlap VALU); s0/s1 reduced in ONE float2
// barrier; bias re-gathered L1-hot at P-pack. setprio(1) wraps both MFMA clusters.
__global__ __launch_bounds__(256, 4)
void attn_kernel(short* Qb,                           // NOT restrict: O aliases Q
                 const short* __restrict__ Kfrag,
                 const short* __restrict__ Vfrag,
                 const float* __restrict__ bias2e,    // [8][4096]
                 const int* __restrict__ rpe_p,
                 float* __restrict__ out2)            // softmax(dots0) [B,H,N,N]
{
  __shared__ __align__(16) char arena[16640];  // P_c[16][520]bf16 | buf[4][16][65]f32
  __shared__ float red0[4][16];
  __shared__ float2 red2[4][16];

  const int t = threadIdx.x;
  const int lane = t & 63, wv = t >> 6;
  const int rg = lane >> 4, cl = lane & 15;

  const int id = blockIdx.x;                 // XCD-swizzled (bijective)
  const int bh = (id & 7) * 8 + ((id >> 3) & 7);
  const int i0 = (id >> 6) * 16;
  const int b = bh >> 3, h = bh & 7;
  const size_t rowbase = (size_t)b * N_TOK;
  const int userpe = rpe_p[0];

  // ---- Q fragments ----
  const size_t qoff = (rowbase + i0 + cl) * 512 + h * DIM_HEAD;
  const bf16x8 qf0 = *(const bf16x8*)&Qb[qoff + rg * 8];
  const bf16x8 qf1 = *(const bf16x8*)&Qb[qoff + 32 + rg * 8];

  // ---- QK^T (swapped), lane-linear fragment loads ----
  const short* kf = Kfrag + (((size_t)bh * 16) * 8 + wv * 2) * 512 + lane * 8;
  f32x4 sc[16];
  __builtin_amdgcn_s_setprio(1);
  {
    bf16x8 a0 = *(const bf16x8*)&kf[0];
    bf16x8 a1 = *(const bf16x8*)&kf[512];
    #pragma unroll
    for (int tj = 0; tj < 16; ++tj) {
      bf16x8 n0, n1;
      if (tj < 15) {
        n0 = *(const bf16x8*)&kf[(tj + 1) * 4096];
        n1 = *(const bf16x8*)&kf[(tj + 1) * 4096 + 512];
      }
      f32x4 z = (f32x4){0.f, 0.f, 0.f, 0.f};
      z = MFMA16(a0, qf0, z, 0, 0, 0);
      z = MFMA16(a1, qf1, z, 0, 0, 0);
      sc[tj] = z;
      a0 = n0; a1 = n1;
    }
  }
  __builtin_amdgcn_s_setprio(0);

  // ---- max reduce (raw scores; scale folded into exp arg) ----
  float m = -1e30f;
  #pragma unroll
  for (int tj = 0; tj < 16; ++tj)
    #pragma unroll
    for (int r = 0; r < 4; ++r) m = fmaxf(m, sc[tj][r]);
  m = fmaxf(m, __shfl_xor(m, 16));
  m = fmaxf(m, __shfl_xor(m, 32));
  if (lane < 16) red0[wv][lane] = m;
  lds_barrier();                                           // barrier 1
  m = fmaxf(fmaxf(red0[0][cl], red0[1][cl]), fmaxf(red0[2][cl], red0[3][cl]));

  // ---- exp pass + fused (s0, s1) partial sums; bias gathered here (overlaps VALU) ----
  const int i_row = i0 + cl;
  const int ri = i_row >> 5, ci = i_row & 31;
  const float* bt = bias2e + (h << 12);
  const int C = (ri - (wv >> 1)) * 63 + ci - ((wv & 1) * 16 + rg * 4) + 1984;
  float s0 = 0.f, s1 = 0.f;
  #pragma unroll
  for (int tj = 0; tj < 16; ++tj) {
    float e0 = __expf((sc[tj][0] - m) * 0.125f);
    float e1 = __expf((sc[tj][1] - m) * 0.125f);
    float e2 = __expf((sc[tj][2] - m) * 0.125f);
    float e3 = __expf((sc[tj][3] - m) * 0.125f);
    sc[tj][0] = e0; sc[tj][1] = e1; sc[tj][2] = e2; sc[tj][3] = e3;
    s0 += (e0 + e1) + (e2 + e3);
    if (userpe) {
      f32x4u bv = *(const f32x4u*)&bt[C - tj * 126 - 3];   // [r3, r2, r1, r0]
      s1 += (e0 * bv[3] + e1 * bv[2]) + (e2 * bv[1] + e3 * bv[0]);
    }
  }
  if (!userpe) s1 = s0;
  s0 += __shfl_xor(s0, 16);  s1 += __shfl_xor(s1, 16);
  s0 += __shfl_xor(s0, 32);  s1 += __shfl_xor(s1, 32);
  if (lane < 16) red2[wv][lane] = make_float2(s0, s1);
  lds_barrier();                                           // barrier 2
  float2 a0r = red2[0][cl], a1r = red2[1][cl], a2r = red2[2][cl], a3r = red2[3][cl];
  const float iv0 = 1.f / (a0r.x + a1r.x + a2r.x + a3r.x);
  const float iv1 = 1.f / (a0r.y + a1r.y + a2r.y + a3r.y);

  // ---- out2: direct 16B plain stores (lane's 4 r = consecutive j), fire-and-forget ----
  {
    float* o2p = out2 + ((size_t)(b * HEADS + h) * N_TOK + i0 + cl) * N_TOK + wv * 16 + rg * 4;
    #pragma unroll
    for (int tj = 0; tj < 16; ++tj) {
      f32x4 vd;
      vd[0] = sc[tj][0] * iv0; vd[1] = sc[tj][1] * iv0;
      vd[2] = sc[tj][2] * iv0; vd[3] = sc[tj][3] * iv0;
      *(f32x4*)&o2p[tj * 64] = vd;
    }
  }

  // ---- chunked P pack (bias re-gathered L1-hot) + PV ----
  unsigned short* P_c = (unsigned short*)arena;    // [16 i][4 wv x 130] pitch 520
  const short* vf = Vfrag + (((size_t)bh * 8) * 16 + wv * 4) * 512 + lane * 8;
  f32x4 oacc[4];
  #pragma unroll
  for (int dt = 0; dt < 4; ++dt) oacc[dt] = (f32x4){0.f, 0.f, 0.f, 0.f};
  #pragma unroll
  for (int ch = 0; ch < 2; ++ch) {
    #pragma unroll
    for (int tj8 = 0; tj8 < 8; ++tj8) {
      int tj = ch * 8 + tj8;
      float v0, v1, v2, v3;
      if (userpe) {
        f32x4u bv = *(const f32x4u*)&bt[C - tj * 126 - 3];
        v0 = sc[tj][0] * bv[3] * iv1; v1 = sc[tj][1] * bv[2] * iv1;
        v2 = sc[tj][2] * bv[1] * iv1; v3 = sc[tj][3] * bv[0] * iv1;
      } else {
        v0 = sc[tj][0] * iv1; v1 = sc[tj][1] * iv1;
        v2 = sc[tj][2] * iv1; v3 = sc[tj][3] * iv1;
      }
      uint2 uu; uu.x = pack2bf(v0, v1); uu.y = pack2bf(v2, v3);
      *(uint2*)&P_c[cl * 520 + wv * 130 + tj8 * 16 + rg * 4] = uu;
    }
    __builtin_amdgcn_s_setprio(1);
    #pragma unroll
    for (int w4 = 0; w4 < 4; ++w4) {
      int w = ch * 4 + w4;
      int tjr = (2 * w + (rg >> 1)) & 7;
      bf16x8 pb = *(const bf16x8*)&P_c[cl * 520 + wv * 130 + tjr * 16 + (rg & 1) * 8];
      #pragma unroll
      for (int dt = 0; dt < 4; ++dt) {
        bf16x8 va = *(const bf16x8*)&vf[w * 8192 + dt * 512];
        oacc[dt] = MFMA16(va, pb, oacc[dt], 0, 0, 0);
      }
    }
    __builtin_amdgcn_s_setprio(0);
  }

  // ---- cross-wave O reduction ----
  lds_barrier();                                           // barrier 3
  float* buf = (float*)arena;                       // [4][16][65]
  #pragma unroll
  for (int dt = 0; dt < 4; ++dt)
    #pragma unroll
    for (int r = 0; r < 4; ++r)
      buf[wv * 1040 + cl * 65 + dt * 16 + rg * 4 + r] = oacc[dt][r];
  lds_barrier();                                           // barrier 4

  const int i_ = t >> 4, dq = t & 15;
  float o[4];
  #pragma unroll
  for (int k = 0; k < 4; ++k) {
    int d = dq * 4 + k;
    o[k] = buf[0 * 1040 + i_ * 65 + d] + buf[1 * 1040 + i_ * 65 + d]
         + buf[2 * 1040 + i_ * 65 + d] + buf[3 * 1040 + i_ * 65 + d];
  }
  short4 os;
  os.x = f2bf(o[0]); os.y = f2bf(o[1]); os.z = f2bf(o[2]); os.w = f2bf(o[3]);
  *(short4*)&Qb[(rowbase + i0 + i_) * 512 + h * DIM_HEAD + dq * 4] = os;  // O in-place
}

extern "C" void kernel_launch(void* const* d_in, const int* in_sizes, int n_in,
                              void* d_out, int out_size, void* d_ws, size_t ws_size,
                              hipStream_t stream) {
  const float* x    = (const float*)d_in[0];
  const float* Wqkv = (const float*)d_in[1];
  const float* Wout = (const float*)d_in[2];
  const float* bout = (const float*)d_in[3];
  const float* rel  = (const float*)d_in[4];
  const float* sita = (const float*)d_in[5];
  const int*   rpe  = (const int*)d_in[6];

  char* ws = (char*)d_ws;
  short* xb     = (short*)(ws);                 //  8 MB  x bf16
  short* WqT    = (short*)(ws + 8388608);       //  1.5MB W_qkv^T
  short* WoT    = (short*)(ws + 9961472);       //  0.5MB W_out^T
  short* Qbuf   = (short*)(ws + 10485760);      //  8 MB  Q [8192][512]; becomes O in-place
  short* Kfrag  = (short*)(ws + 18874368);      //  8 MB  K fragments
  float* bias2e = (float*)(ws + 27262976);      // 128 KB exp'd fused bias [8][4096]
  short* Vfrag  = (short*)(ws + 35651584);      //  8 MB  V fragments

  float* out1 = (float*)d_out;
  float* out2 = out1 + (size_t)BATCH * N_TOK * DIMM;

  hipLaunchKernelGGL(prep_kernel, dim3(8320), dim3(256), 0, stream,
                     x, xb, Wqkv, WqT, Wout, WoT, rel, sita, bias2e);
  hipLaunchKernelGGL((gemm_kernel<1>), dim3(12, 64), dim3(256), 0, stream,
                     xb, WqT, (void*)nullptr, (const float*)nullptr,
                     Qbuf, Kfrag, Vfrag, 8192, 1536, 512, 512);
  hipLaunchKernelGGL(attn_kernel, dim3(4096), dim3(256), 0, stream,
                     Qbuf, Kfrag, Vfrag, bias2e, rpe, out2);
  hipLaunchKernelGGL((gemm_kernel<0>), dim3(4, 64), dim3(256), 0, stream,
                     Qbuf, WoT, d_out, bout,
                     (short*)nullptr, (short*)nullptr, (short*)nullptr, 8192, 512, 512, 512);
}

// Round 17
// 151.867 us; speedup vs baseline: 1.1314x; 1.1314x over previous
//
#include <hip/hip_runtime.h>
#include <hip/hip_bf16.h>

typedef __attribute__((ext_vector_type(8))) short bf16x8;
typedef __attribute__((ext_vector_type(4))) float f32x4;
typedef float f32x4u __attribute__((ext_vector_type(4), aligned(4)));  // dword-aligned vec4
typedef __attribute__((ext_vector_type(4))) unsigned int uint32x4;

#define N_TOK 1024
#define HEADS 8
#define DIM_HEAD 64
#define BATCH 8
#define DIMM 512
#define INNER 512
#define QKV_COLS 1536

#define MFMA16 __builtin_amdgcn_mfma_f32_16x16x32_bf16

__device__ inline short f2bf(float f) {
  union { float f; unsigned u; } v;
  v.f = f;
  unsigned r = v.u + 0x7fffu + ((v.u >> 16) & 1u);  // RNE
  return (short)(r >> 16);
}

__device__ inline unsigned pack2bf(float a, float b) {
  return ((unsigned)(unsigned short)f2bf(a)) | (((unsigned)(unsigned short)f2bf(b)) << 16);
}

// LDS-only barrier: orders LDS across waves WITHOUT draining global stores
__device__ inline void lds_barrier() {
  asm volatile("s_waitcnt lgkmcnt(0)" ::: "memory");
  __builtin_amdgcn_s_barrier();
  asm volatile("" ::: "memory");
}

// direct global->LDS 16B/lane (dest = wave-uniform base + lane*16)
__device__ inline void gload_lds16(const short* g, short* l) {
  __builtin_amdgcn_global_load_lds(
      (const __attribute__((address_space(1))) void*)g,
      (__attribute__((address_space(3))) void*)l, 16, 0, 0);
}

// ---------------- merged prep: x->bf16 | Wqkv^T (LDS tile) | Wout^T (LDS tile) | bias2e ----
// Block ranges: [0,4096) x-convert; [4096,4288) Wqkv tiles (192); [4288,4352) Wout
// tiles (64); [4352,4480) bias2e. (R16 crash was blocks 4352..4479 mis-entering the
// Wout branch with OOB tile indices.)
__global__ __launch_bounds__(256)
void prep_kernel(const float* __restrict__ x, short* __restrict__ xb,
                 const float* __restrict__ Wqkv, short* __restrict__ WqT,
                 const float* __restrict__ Wout, short* __restrict__ WoT,
                 const float* __restrict__ rel, const float* __restrict__ headsita,
                 float* __restrict__ bias2e) {
  __shared__ short Tt[64][65];
  const int blk = blockIdx.x, t = threadIdx.x;
  if (blk < 4096) {                      // x fp32 -> bf16 (4M elems, x4/thread)
    int i = (blk * 256 + t) * 4;
    float4 v = *(const float4*)&x[i];
    short4 o;
    o.x = f2bf(v.x); o.y = f2bf(v.y); o.z = f2bf(v.z); o.w = f2bf(v.w);
    *(short4*)&xb[i] = o;
  } else if (blk < 4352) {               // weight transpose tiles
    const float* W; short* Wt; int Ncols, kt, nt;
    if (blk < 4288) {                    // Wqkv [512][1536]: 8 kt x 24 nt = 192 tiles
      int tt = blk - 4096;
      W = Wqkv; Wt = WqT; Ncols = 1536; kt = tt / 24; nt = tt % 24;
    } else {                             // Wout [512][512]: 8 kt x 8 nt = 64 tiles
      int tt = blk - 4288;
      W = Wout; Wt = WoT; Ncols = 512; kt = tt >> 3; nt = tt & 7;
    }
    {
      int r = t >> 2, cchunk = (t & 3) * 16;
      const float* src = &W[(size_t)(kt * 64 + r) * Ncols + nt * 64 + cchunk];
      #pragma unroll
      for (int q = 0; q < 4; ++q) {
        float4 v = *(const float4*)&src[q * 4];
        Tt[r][cchunk + q*4 + 0] = f2bf(v.x);
        Tt[r][cchunk + q*4 + 1] = f2bf(v.y);
        Tt[r][cchunk + q*4 + 2] = f2bf(v.z);
        Tt[r][cchunk + q*4 + 3] = f2bf(v.w);
      }
    }
    lds_barrier();
    {
      int nl = t >> 2, kchunk = (t & 3) * 16;
      short tmp[16];
      #pragma unroll
      for (int j = 0; j < 16; ++j) tmp[j] = Tt[kchunk + j][nl];
      short* dst = &Wt[(size_t)(nt * 64 + nl) * 512 + kt * 64 + kchunk];
      *(int4*)&dst[0] = *(int4*)&tmp[0];
      *(int4*)&dst[8] = *(int4*)&tmp[8];
    }
  } else {                               // bias2e [8][4096] (128 blocks)
    int e = (blk - 4352) * 256 + t;
    int h = e >> 12, idx = e & 4095;
    if (idx >= 3969) return;
    int dr = idx / 63 - 31;
    int dc = idx % 63 - 31;
    float th = headsita[h];
    float factor = 1.f / (2.f * th * th + 1e-10f);
    float dis = (float)(dr * dr + dc * dc) * (1.0f / 1024.0f);
    bias2e[e] = __expf(rel[idx * HEADS + h] + 0.01f * __expf(-factor * dis));
  }
}

// ---------------- bf16 MFMA GEMM, m97-style staging (unchanged from R13) ----------------
template<int SPLIT>
__global__ __launch_bounds__(256)
void gemm_kernel(const short* __restrict__ A, const short* __restrict__ Bt,
                 void* __restrict__ C, const float* __restrict__ bias,
                 short* __restrict__ Qb, short* __restrict__ Kfrag,
                 short* __restrict__ Vfrag,
                 int M, int Nc, int K, int lda)
{
  __shared__ short Ash[128 * 32];   // linear row-major [128][32] (gload_lds dest)
  __shared__ short Bsh[128 * 32];
  const int t = threadIdx.x;
  const int lane = t & 63, wave = t >> 6;
  const int wm = wave >> 1, wn = wave & 1;
  const int m0 = blockIdx.y * 128, n0 = blockIdx.x * 128;
  const int grow = wave * 32 + (lane >> 2);
  const int gcol = (lane & 3) * 8;
  f32x4 acc[4][4] = {};
  for (int k0 = 0; k0 < K; k0 += 32) {
    lds_barrier();
    #pragma unroll
    for (int i = 0; i < 2; ++i) {
      gload_lds16(&A[(size_t)(m0 + grow + i * 16) * lda + k0 + gcol],
                  &Ash[(wave * 32 + i * 16) * 32]);
      gload_lds16(&Bt[(size_t)(n0 + grow + i * 16) * K + k0 + gcol],
                  &Bsh[(wave * 32 + i * 16) * 32]);
    }
    asm volatile("s_waitcnt vmcnt(0)" ::: "memory");
    __builtin_amdgcn_s_barrier();
    asm volatile("" ::: "memory");
    bf16x8 af[4], bfr[4];
    #pragma unroll
    for (int m = 0; m < 4; ++m)
      af[m] = *(const bf16x8*)&Ash[(wm * 64 + m * 16 + (lane & 15)) * 32 + (lane >> 4) * 8];
    #pragma unroll
    for (int n = 0; n < 4; ++n)
      bfr[n] = *(const bf16x8*)&Bsh[(wn * 64 + n * 16 + (lane & 15)) * 32 + (lane >> 4) * 8];
    #pragma unroll
    for (int m = 0; m < 4; ++m)
      #pragma unroll
      for (int n = 0; n < 4; ++n)
        acc[m][n] = MFMA16(af[m], bfr[n], acc[m][n], 0, 0, 0);
  }
  const int r0 = (lane >> 4) * 4, c0 = lane & 15;
  if (!SPLIT) {
    #pragma unroll
    for (int m = 0; m < 4; ++m)
      #pragma unroll
      for (int n = 0; n < 4; ++n) {
        int col = n0 + wn*64 + n*16 + c0;
        float bv = bias[col];
        #pragma unroll
        for (int r = 0; r < 4; ++r) {
          int row = m0 + wm*64 + m*16 + r0 + r;
          ((float*)C)[(size_t)row * Nc + col] = acc[m][n][r] + bv;
        }
      }
  } else {
    const int seg = n0 >> 9;   // 0=Q, 1=K, 2=V (each 512 cols = 4 blocks)
    #pragma unroll
    for (int m = 0; m < 4; ++m)
      #pragma unroll
      for (int n = 0; n < 4; ++n) {
        const int colg = n0 + wn*64 + n*16 + c0;
        const int rowg0 = m0 + wm*64 + m*16 + r0;
        if (seg == 0) {
          #pragma unroll
          for (int rr = 0; rr < 4; ++rr)
            Qb[(size_t)(rowg0 + rr) * 512 + colg] = f2bf(acc[m][n][rr]);
        } else if (seg == 1) {
          const int d = colg - 512, h = d >> 6, dd = d & 63;
          const int b = rowg0 >> 10, j0 = rowg0 & 1023;
          const size_t base = ((((size_t)(b * 8 + h) * 16 + (j0 >> 6)) * 8)
                               + ((j0 >> 4) & 3) * 2 + (dd >> 5)) * 512
                              + ((dd >> 3) & 3) * 128 + (dd & 7);
          #pragma unroll
          for (int rr = 0; rr < 4; ++rr)
            Kfrag[base + ((j0 + rr) & 15) * 8] = f2bf(acc[m][n][rr]);
        } else {
          const int d = colg - 1024, h = d >> 6, dd = d & 63;
          const int b = rowg0 >> 10, j0 = rowg0 & 1023;
          const int w = j0 >> 7, j7 = j0 & 127;
          const int rgv = (((j7 >> 6) & 1) << 1) | ((j7 >> 3) & 1);
          const int wvv = (j7 >> 4) & 3, e0 = j7 & 7;   // e0 in {0,4}
          const size_t addr = (((size_t)(b * 8 + h) * 8 + w) * 16 + wvv * 4 + (dd >> 4)) * 512
                              + (rgv * 16 + (dd & 15)) * 8 + e0;
          short4 sv;
          sv.x = f2bf(acc[m][n][0]); sv.y = f2bf(acc[m][n][1]);
          sv.z = f2bf(acc[m][n][2]); sv.w = f2bf(acc[m][n][3]);
          *(short4*)&Vfrag[addr] = sv;
        }
      }
  }
}

// ---------------- fused attention v17: R13 structure + 2-deep K / 1-ahead V prefetch ----------------
__global__ __launch_bounds__(256, 4)
void attn_kernel(short* Qb,                           // NOT restrict: O aliases Q
                 const short* __restrict__ Kfrag,
                 const short* __restrict__ Vfrag,
                 const float* __restrict__ bias2e,    // [8][4096]
                 const int* __restrict__ rpe_p,
                 float* __restrict__ out2)            // softmax(dots0) [B,H,N,N]
{
  __shared__ __align__(16) char arena[17408];  // stage[256*17]f32 | P_c[16][520]bf16 | buf
  __shared__ float red0[4][16];
  __shared__ float red1[4][16];

  const int t = threadIdx.x;
  const int lane = t & 63, wv = t >> 6;
  const int rg = lane >> 4, cl = lane & 15;

  const int id = blockIdx.x;                 // XCD-swizzled (bijective)
  const int bh = (id & 7) * 8 + ((id >> 3) & 7);
  const int i0 = (id >> 6) * 16;
  const int b = bh >> 3, h = bh & 7;
  const size_t rowbase = (size_t)b * N_TOK;

  // ---- Q fragments ----
  const size_t qoff = (rowbase + i0 + cl) * 512 + h * DIM_HEAD;
  const bf16x8 qf0 = *(const bf16x8*)&Qb[qoff + rg * 8];
  const bf16x8 qf1 = *(const bf16x8*)&Qb[qoff + 32 + rg * 8];

  // ---- QK^T (swapped), lane-linear fragment loads, 2-deep prefetch ----
  const short* kf = Kfrag + (((size_t)bh * 16) * 8 + wv * 2) * 512 + lane * 8;
  f32x4 sc[16];
  {
    bf16x8 p0a = *(const bf16x8*)&kf[0];
    bf16x8 p0b = *(const bf16x8*)&kf[512];
    bf16x8 p1a = *(const bf16x8*)&kf[4096];
    bf16x8 p1b = *(const bf16x8*)&kf[4096 + 512];
    #pragma unroll
    for (int tj = 0; tj < 16; ++tj) {
      bf16x8 c0 = p0a, c1 = p0b;
      p0a = p1a; p0b = p1b;
      if (tj < 14) {
        p1a = *(const bf16x8*)&kf[(tj + 2) * 4096];
        p1b = *(const bf16x8*)&kf[(tj + 2) * 4096 + 512];
      }
      f32x4 z = (f32x4){0.f, 0.f, 0.f, 0.f};
      z = MFMA16(c0, qf0, z, 0, 0, 0);
      z = MFMA16(c1, qf1, z, 0, 0, 0);
      sc[tj] = z;
    }
  }

  // ---- softmax0 on RAW scores (scale folded into exp arg) ----
  float m = -1e30f;
  #pragma unroll
  for (int tj = 0; tj < 16; ++tj)
    #pragma unroll
    for (int r = 0; r < 4; ++r) m = fmaxf(m, sc[tj][r]);
  m = fmaxf(m, __shfl_xor(m, 16));
  m = fmaxf(m, __shfl_xor(m, 32));
  if (lane < 16) red0[wv][lane] = m;
  lds_barrier();
  m = fmaxf(fmaxf(red0[0][cl], red0[1][cl]), fmaxf(red0[2][cl], red0[3][cl]));

  float s = 0.f;
  #pragma unroll
  for (int tj = 0; tj < 16; ++tj)
    #pragma unroll
    for (int r = 0; r < 4; ++r) {
      float e = __expf((sc[tj][r] - m) * 0.125f);
      sc[tj][r] = e;
      s += e;
    }
  s += __shfl_xor(s, 16);
  s += __shfl_xor(s, 32);
  if (lane < 16) red1[wv][lane] = s;
  lds_barrier();
  const float sm0 = red1[0][cl] + red1[1][cl] + red1[2][cl] + red1[3][cl];
  const float iv0 = 1.f / sm0;

  // ---- out2 via LDS transpose chunks, full-line stores (R13 staging) ----
  float* stage = (float*)arena;                    // [256][17] f32
  const size_t o2base = ((size_t)(b * HEADS + h) * N_TOK + i0) * N_TOK;
  #pragma unroll
  for (int c = 0; c < 4; ++c) {
    #pragma unroll
    for (int tjl = 0; tjl < 4; ++tjl)
      #pragma unroll
      for (int r = 0; r < 4; ++r)
        stage[(tjl * 64 + wv * 16 + rg * 4 + r) * 17 + cl] = sc[c * 4 + tjl][r] * iv0;
    lds_barrier();
    #pragma unroll
    for (int k = 0; k < 4; ++k) {
      int row = wv * 4 + k;
      #pragma unroll
      for (int e = 0; e < 4; ++e) {
        float v = stage[(e * 64 + lane) * 17 + row];
        out2[o2base + (size_t)row * N_TOK + c * 256 + e * 64 + lane] = v;
      }
    }
    lds_barrier();
  }

  // ---- P = e0 * exp(bias) / sum1 -- vectorized affine-idx loads ----
  const int i_row = i0 + cl;
  const int ri = i_row >> 5, ci = i_row & 31;
  float iv1;
  const float* bt = bias2e + (h << 12);
  const int C = (ri - (wv >> 1)) * 63 + ci - ((wv & 1) * 16 + rg * 4) + 1984;
  if (rpe_p[0]) {
    float s1 = 0.f;
    #pragma unroll
    for (int tj = 0; tj < 16; ++tj) {
      f32x4u bv = *(const f32x4u*)&bt[C - tj * 126 - 3];   // [r3, r2, r1, r0]
      float v0 = sc[tj][0] * bv[3];
      float v1 = sc[tj][1] * bv[2];
      float v2 = sc[tj][2] * bv[1];
      float v3 = sc[tj][3] * bv[0];
      sc[tj][0] = v0; sc[tj][1] = v1; sc[tj][2] = v2; sc[tj][3] = v3;
      s1 += (v0 + v1) + (v2 + v3);
    }
    s1 += __shfl_xor(s1, 16);
    s1 += __shfl_xor(s1, 32);
    if (lane < 16) red0[wv][lane] = s1;
    lds_barrier();
    iv1 = 1.f / (red0[0][cl] + red0[1][cl] + red0[2][cl] + red0[3][cl]);
  } else {
    iv1 = iv0;
  }

  // ---- chunked P pack + PV (wave-private half-passes), V ping-pong prefetch ----
  unsigned short* P_c = (unsigned short*)arena;    // [16 i][4 wv x 130] pitch 520
  const short* vf = Vfrag + (((size_t)bh * 8) * 16 + wv * 4) * 512 + lane * 8;
  f32x4 oacc[4];
  #pragma unroll
  for (int dt = 0; dt < 4; ++dt) oacc[dt] = (f32x4){0.f, 0.f, 0.f, 0.f};
  bf16x8 vc0 = *(const bf16x8*)&vf[0];
  bf16x8 vc1 = *(const bf16x8*)&vf[512];
  bf16x8 vc2 = *(const bf16x8*)&vf[1024];
  bf16x8 vc3 = *(const bf16x8*)&vf[1536];
  #pragma unroll
  for (int ch = 0; ch < 2; ++ch) {
    #pragma unroll
    for (int tj8 = 0; tj8 < 8; ++tj8) {
      int tj = ch * 8 + tj8;
      unsigned u0 = pack2bf(sc[tj][0] * iv1, sc[tj][1] * iv1);
      unsigned u1 = pack2bf(sc[tj][2] * iv1, sc[tj][3] * iv1);
      uint2 uu; uu.x = u0; uu.y = u1;
      *(uint2*)&P_c[cl * 520 + wv * 130 + tj8 * 16 + rg * 4] = uu;
    }
    #pragma unroll
    for (int w4 = 0; w4 < 4; ++w4) {
      int w = ch * 4 + w4;
      bf16x8 vn0, vn1, vn2, vn3;
      if (w < 7) {
        vn0 = *(const bf16x8*)&vf[(w + 1) * 8192];
        vn1 = *(const bf16x8*)&vf[(w + 1) * 8192 + 512];
        vn2 = *(const bf16x8*)&vf[(w + 1) * 8192 + 1024];
        vn3 = *(const bf16x8*)&vf[(w + 1) * 8192 + 1536];
      }
      int tjr = (2 * w + (rg >> 1)) & 7;
      bf16x8 pb = *(const bf16x8*)&P_c[cl * 520 + wv * 130 + tjr * 16 + (rg & 1) * 8];
      oacc[0] = MFMA16(vc0, pb, oacc[0], 0, 0, 0);
      oacc[1] = MFMA16(vc1, pb, oacc[1], 0, 0, 0);
      oacc[2] = MFMA16(vc2, pb, oacc[2], 0, 0, 0);
      oacc[3] = MFMA16(vc3, pb, oacc[3], 0, 0, 0);
      vc0 = vn0; vc1 = vn1; vc2 = vn2; vc3 = vn3;
    }
  }

  // ---- cross-wave O reduction ----
  lds_barrier();                                    // all P_c reads done before overwrite
  float* buf = (float*)arena;                       // [4][16][65]
  #pragma unroll
  for (int dt = 0; dt < 4; ++dt)
    #pragma unroll
    for (int r = 0; r < 4; ++r)
      buf[wv * 1040 + cl * 65 + dt * 16 + rg * 4 + r] = oacc[dt][r];
  lds_barrier();

  const int i_ = t >> 4, dq = t & 15;
  float o[4];
  #pragma unroll
  for (int k = 0; k < 4; ++k) {
    int d = dq * 4 + k;
    o[k] = buf[0 * 1040 + i_ * 65 + d] + buf[1 * 1040 + i_ * 65 + d]
         + buf[2 * 1040 + i_ * 65 + d] + buf[3 * 1040 + i_ * 65 + d];
  }
  short4 os;
  os.x = f2bf(o[0]); os.y = f2bf(o[1]); os.z = f2bf(o[2]); os.w = f2bf(o[3]);
  *(short4*)&Qb[(rowbase + i0 + i_) * 512 + h * DIM_HEAD + dq * 4] = os;  // O in-place
}

extern "C" void kernel_launch(void* const* d_in, const int* in_sizes, int n_in,
                              void* d_out, int out_size, void* d_ws, size_t ws_size,
                              hipStream_t stream) {
  const float* x    = (const float*)d_in[0];
  const float* Wqkv = (const float*)d_in[1];
  const float* Wout = (const float*)d_in[2];
  const float* bout = (const float*)d_in[3];
  const float* rel  = (const float*)d_in[4];
  const float* sita = (const float*)d_in[5];
  const int*   rpe  = (const int*)d_in[6];

  char* ws = (char*)d_ws;
  short* xb     = (short*)(ws);                 //  8 MB  x bf16
  short* WqT    = (short*)(ws + 8388608);       //  1.5MB W_qkv^T
  short* WoT    = (short*)(ws + 9961472);       //  0.5MB W_out^T
  short* Qbuf   = (short*)(ws + 10485760);      //  8 MB  Q [8192][512]; becomes O in-place
  short* Kfrag  = (short*)(ws + 18874368);      //  8 MB  K fragments
  float* bias2e = (float*)(ws + 27262976);      // 128 KB exp'd fused bias [8][4096]
  short* Vfrag  = (short*)(ws + 35651584);      //  8 MB  V fragments

  float* out1 = (float*)d_out;
  float* out2 = out1 + (size_t)BATCH * N_TOK * DIMM;

  hipLaunchKernelGGL(prep_kernel, dim3(4480), dim3(256), 0, stream,
                     x, xb, Wqkv, WqT, Wout, WoT, rel, sita, bias2e);
  hipLaunchKernelGGL((gemm_kernel<1>), dim3(12, 64), dim3(256), 0, stream,
                     xb, WqT, (void*)nullptr, (const float*)nullptr,
                     Qbuf, Kfrag, Vfrag, 8192, 1536, 512, 512);
  hipLaunchKernelGGL(attn_kernel, dim3(4096), dim3(256), 0, stream,
                     Qbuf, Kfrag, Vfrag, bias2e, rpe, out2);
  hipLaunchKernelGGL((gemm_kernel<0>), dim3(4, 64), dim3(256), 0, stream,
                     Qbuf, WoT, d_out, bout,
                     (short*)nullptr, (short*)nullptr, (short*)nullptr, 8192, 512, 512, 512);
}

// Round 18
// 147.663 us; speedup vs baseline: 1.1636x; 1.0285x over previous
//
#include <hip/hip_runtime.h>
#include <hip/hip_bf16.h>

typedef __attribute__((ext_vector_type(8))) short bf16x8;
typedef __attribute__((ext_vector_type(4))) float f32x4;
typedef float f32x4u __attribute__((ext_vector_type(4), aligned(4)));  // dword-aligned vec4
typedef __attribute__((ext_vector_type(4))) unsigned int uint32x4;

#define N_TOK 1024
#define HEADS 8
#define DIM_HEAD 64
#define BATCH 8
#define DIMM 512
#define INNER 512
#define QKV_COLS 1536

#define MFMA16 __builtin_amdgcn_mfma_f32_16x16x32_bf16

__device__ inline short f2bf(float f) {
  union { float f; unsigned u; } v;
  v.f = f;
  unsigned r = v.u + 0x7fffu + ((v.u >> 16) & 1u);  // RNE
  return (short)(r >> 16);
}

__device__ inline unsigned pack2bf(float a, float b) {
  return ((unsigned)(unsigned short)f2bf(a)) | (((unsigned)(unsigned short)f2bf(b)) << 16);
}

// LDS-only barrier: orders LDS across waves WITHOUT draining global stores
__device__ inline void lds_barrier() {
  asm volatile("s_waitcnt lgkmcnt(0)" ::: "memory");
  __builtin_amdgcn_s_barrier();
  asm volatile("" ::: "memory");
}

// direct global->LDS 16B/lane (dest = wave-uniform base + lane*16)
__device__ inline void gload_lds16(const short* g, short* l) {
  __builtin_amdgcn_global_load_lds(
      (const __attribute__((address_space(1))) void*)g,
      (__attribute__((address_space(3))) void*)l, 16, 0, 0);
}

// ---------------- merged prep: x->bf16 | Wqkv^T (LDS tile) | Wout^T (LDS tile) | bias2e ----
__global__ __launch_bounds__(256)
void prep_kernel(const float* __restrict__ x, short* __restrict__ xb,
                 const float* __restrict__ Wqkv, short* __restrict__ WqT,
                 const float* __restrict__ Wout, short* __restrict__ WoT,
                 const float* __restrict__ rel, const float* __restrict__ headsita,
                 float* __restrict__ bias2e) {
  __shared__ short Tt[64][65];
  const int blk = blockIdx.x, t = threadIdx.x;
  if (blk < 4096) {                      // x fp32 -> bf16 (4M elems, x4/thread)
    int i = (blk * 256 + t) * 4;
    float4 v = *(const float4*)&x[i];
    short4 o;
    o.x = f2bf(v.x); o.y = f2bf(v.y); o.z = f2bf(v.z); o.w = f2bf(v.w);
    *(short4*)&xb[i] = o;
  } else if (blk < 4352) {               // weight transpose tiles
    const float* W; short* Wt; int Ncols, kt, nt;
    if (blk < 4288) {                    // Wqkv [512][1536]: 8 kt x 24 nt = 192 tiles
      int tt = blk - 4096;
      W = Wqkv; Wt = WqT; Ncols = 1536; kt = tt / 24; nt = tt % 24;
    } else {                             // Wout [512][512]: 8 kt x 8 nt = 64 tiles
      int tt = blk - 4288;
      W = Wout; Wt = WoT; Ncols = 512; kt = tt >> 3; nt = tt & 7;
    }
    {
      int r = t >> 2, cchunk = (t & 3) * 16;
      const float* src = &W[(size_t)(kt * 64 + r) * Ncols + nt * 64 + cchunk];
      #pragma unroll
      for (int q = 0; q < 4; ++q) {
        float4 v = *(const float4*)&src[q * 4];
        Tt[r][cchunk + q*4 + 0] = f2bf(v.x);
        Tt[r][cchunk + q*4 + 1] = f2bf(v.y);
        Tt[r][cchunk + q*4 + 2] = f2bf(v.z);
        Tt[r][cchunk + q*4 + 3] = f2bf(v.w);
      }
    }
    lds_barrier();
    {
      int nl = t >> 2, kchunk = (t & 3) * 16;
      short tmp[16];
      #pragma unroll
      for (int j = 0; j < 16; ++j) tmp[j] = Tt[kchunk + j][nl];
      short* dst = &Wt[(size_t)(nt * 64 + nl) * 512 + kt * 64 + kchunk];
      *(int4*)&dst[0] = *(int4*)&tmp[0];
      *(int4*)&dst[8] = *(int4*)&tmp[8];
    }
  } else {                               // bias2e [8][4096] (128 blocks)
    int e = (blk - 4352) * 256 + t;
    int h = e >> 12, idx = e & 4095;
    if (idx >= 3969) return;
    int dr = idx / 63 - 31;
    int dc = idx % 63 - 31;
    float th = headsita[h];
    float factor = 1.f / (2.f * th * th + 1e-10f);
    float dis = (float)(dr * dr + dc * dc) * (1.0f / 1024.0f);
    bias2e[e] = __expf(rel[idx * HEADS + h] + 0.01f * __expf(-factor * dis));
  }
}

// ---------------- bf16 MFMA GEMM, m97-style staging (unchanged) ----------------
template<int SPLIT>
__global__ __launch_bounds__(256)
void gemm_kernel(const short* __restrict__ A, const short* __restrict__ Bt,
                 void* __restrict__ C, const float* __restrict__ bias,
                 short* __restrict__ Qb, short* __restrict__ Kfrag,
                 short* __restrict__ Vfrag,
                 int M, int Nc, int K, int lda)
{
  __shared__ short Ash[128 * 32];   // linear row-major [128][32] (gload_lds dest)
  __shared__ short Bsh[128 * 32];
  const int t = threadIdx.x;
  const int lane = t & 63, wave = t >> 6;
  const int wm = wave >> 1, wn = wave & 1;
  const int m0 = blockIdx.y * 128, n0 = blockIdx.x * 128;
  const int grow = wave * 32 + (lane >> 2);
  const int gcol = (lane & 3) * 8;
  f32x4 acc[4][4] = {};
  for (int k0 = 0; k0 < K; k0 += 32) {
    lds_barrier();
    #pragma unroll
    for (int i = 0; i < 2; ++i) {
      gload_lds16(&A[(size_t)(m0 + grow + i * 16) * lda + k0 + gcol],
                  &Ash[(wave * 32 + i * 16) * 32]);
      gload_lds16(&Bt[(size_t)(n0 + grow + i * 16) * K + k0 + gcol],
                  &Bsh[(wave * 32 + i * 16) * 32]);
    }
    asm volatile("s_waitcnt vmcnt(0)" ::: "memory");
    __builtin_amdgcn_s_barrier();
    asm volatile("" ::: "memory");
    bf16x8 af[4], bfr[4];
    #pragma unroll
    for (int m = 0; m < 4; ++m)
      af[m] = *(const bf16x8*)&Ash[(wm * 64 + m * 16 + (lane & 15)) * 32 + (lane >> 4) * 8];
    #pragma unroll
    for (int n = 0; n < 4; ++n)
      bfr[n] = *(const bf16x8*)&Bsh[(wn * 64 + n * 16 + (lane & 15)) * 32 + (lane >> 4) * 8];
    #pragma unroll
    for (int m = 0; m < 4; ++m)
      #pragma unroll
      for (int n = 0; n < 4; ++n)
        acc[m][n] = MFMA16(af[m], bfr[n], acc[m][n], 0, 0, 0);
  }
  const int r0 = (lane >> 4) * 4, c0 = lane & 15;
  if (!SPLIT) {
    #pragma unroll
    for (int m = 0; m < 4; ++m)
      #pragma unroll
      for (int n = 0; n < 4; ++n) {
        int col = n0 + wn*64 + n*16 + c0;
        float bv = bias[col];
        #pragma unroll
        for (int r = 0; r < 4; ++r) {
          int row = m0 + wm*64 + m*16 + r0 + r;
          ((float*)C)[(size_t)row * Nc + col] = acc[m][n][r] + bv;
        }
      }
  } else {
    const int seg = n0 >> 9;   // 0=Q, 1=K, 2=V (each 512 cols = 4 blocks)
    #pragma unroll
    for (int m = 0; m < 4; ++m)
      #pragma unroll
      for (int n = 0; n < 4; ++n) {
        const int colg = n0 + wn*64 + n*16 + c0;
        const int rowg0 = m0 + wm*64 + m*16 + r0;
        if (seg == 0) {
          #pragma unroll
          for (int rr = 0; rr < 4; ++rr)
            Qb[(size_t)(rowg0 + rr) * 512 + colg] = f2bf(acc[m][n][rr]);
        } else if (seg == 1) {
          const int d = colg - 512, h = d >> 6, dd = d & 63;
          const int b = rowg0 >> 10, j0 = rowg0 & 1023;
          const size_t base = ((((size_t)(b * 8 + h) * 16 + (j0 >> 6)) * 8)
                               + ((j0 >> 4) & 3) * 2 + (dd >> 5)) * 512
                              + ((dd >> 3) & 3) * 128 + (dd & 7);
          #pragma unroll
          for (int rr = 0; rr < 4; ++rr)
            Kfrag[base + ((j0 + rr) & 15) * 8] = f2bf(acc[m][n][rr]);
        } else {
          const int d = colg - 1024, h = d >> 6, dd = d & 63;
          const int b = rowg0 >> 10, j0 = rowg0 & 1023;
          const int w = j0 >> 7, j7 = j0 & 127;
          const int rgv = (((j7 >> 6) & 1) << 1) | ((j7 >> 3) & 1);
          const int wvv = (j7 >> 4) & 3, e0 = j7 & 7;   // e0 in {0,4}
          const size_t addr = (((size_t)(b * 8 + h) * 8 + w) * 16 + wvv * 4 + (dd >> 4)) * 512
                              + (rgv * 16 + (dd & 15)) * 8 + e0;
          short4 sv;
          sv.x = f2bf(acc[m][n][0]); sv.y = f2bf(acc[m][n][1]);
          sv.z = f2bf(acc[m][n][2]); sv.w = f2bf(acc[m][n][3]);
          *(short4*)&Vfrag[addr] = sv;
        }
      }
  }
}

// ---------------- fused attention v18: 2-chunk staging (512j) + bias fused into
// store windows. Barriers 13 -> 8; bias gathers overlap out2 stores. ----------------
__global__ __launch_bounds__(256, 4)
void attn_kernel(short* Qb,                           // NOT restrict: O aliases Q
                 const short* __restrict__ Kfrag,
                 const short* __restrict__ Vfrag,
                 const float* __restrict__ bias2e,    // [8][4096]
                 const int* __restrict__ rpe_p,
                 float* __restrict__ out2)            // softmax(dots0) [B,H,N,N]
{
  __shared__ __align__(16) char arena[34816];  // stage[512][17]f32 | P_c[16][520] | buf
  __shared__ float red0[4][16];
  __shared__ float red1[4][16];

  const int t = threadIdx.x;
  const int lane = t & 63, wv = t >> 6;
  const int rg = lane >> 4, cl = lane & 15;

  const int id = blockIdx.x;                 // XCD-swizzled (bijective)
  const int bh = (id & 7) * 8 + ((id >> 3) & 7);
  const int i0 = (id >> 6) * 16;
  const int b = bh >> 3, h = bh & 7;
  const size_t rowbase = (size_t)b * N_TOK;
  const int userpe = rpe_p[0];

  // ---- Q fragments ----
  const size_t qoff = (rowbase + i0 + cl) * 512 + h * DIM_HEAD;
  const bf16x8 qf0 = *(const bf16x8*)&Qb[qoff + rg * 8];
  const bf16x8 qf1 = *(const bf16x8*)&Qb[qoff + 32 + rg * 8];

  // ---- QK^T (swapped), lane-linear fragment loads, 2-deep prefetch ----
  const short* kf = Kfrag + (((size_t)bh * 16) * 8 + wv * 2) * 512 + lane * 8;
  f32x4 sc[16];
  {
    bf16x8 p0a = *(const bf16x8*)&kf[0];
    bf16x8 p0b = *(const bf16x8*)&kf[512];
    bf16x8 p1a = *(const bf16x8*)&kf[4096];
    bf16x8 p1b = *(const bf16x8*)&kf[4096 + 512];
    #pragma unroll
    for (int tj = 0; tj < 16; ++tj) {
      bf16x8 c0 = p0a, c1 = p0b;
      p0a = p1a; p0b = p1b;
      if (tj < 14) {
        p1a = *(const bf16x8*)&kf[(tj + 2) * 4096];
        p1b = *(const bf16x8*)&kf[(tj + 2) * 4096 + 512];
      }
      f32x4 z = (f32x4){0.f, 0.f, 0.f, 0.f};
      z = MFMA16(c0, qf0, z, 0, 0, 0);
      z = MFMA16(c1, qf1, z, 0, 0, 0);
      sc[tj] = z;
    }
  }

  // ---- softmax0 on RAW scores (scale folded into exp arg) ----
  float m = -1e30f;
  #pragma unroll
  for (int tj = 0; tj < 16; ++tj)
    #pragma unroll
    for (int r = 0; r < 4; ++r) m = fmaxf(m, sc[tj][r]);
  m = fmaxf(m, __shfl_xor(m, 16));
  m = fmaxf(m, __shfl_xor(m, 32));
  if (lane < 16) red0[wv][lane] = m;
  lds_barrier();                                           // barrier 1
  m = fmaxf(fmaxf(red0[0][cl], red0[1][cl]), fmaxf(red0[2][cl], red0[3][cl]));

  float s = 0.f;
  #pragma unroll
  for (int tj = 0; tj < 16; ++tj)
    #pragma unroll
    for (int r = 0; r < 4; ++r) {
      float e = __expf((sc[tj][r] - m) * 0.125f);
      sc[tj][r] = e;
      s += e;
    }
  s += __shfl_xor(s, 16);
  s += __shfl_xor(s, 32);
  if (lane < 16) red1[wv][lane] = s;
  lds_barrier();                                           // barrier 2
  const float sm0 = red1[0][cl] + red1[1][cl] + red1[2][cl] + red1[3][cl];
  const float iv0 = 1.f / sm0;

  // ---- out2 via LDS transpose, 2 chunks of 512 j; bias fused into store windows ----
  float* stage = (float*)arena;                    // [512][17] f32
  const size_t o2base = ((size_t)(b * HEADS + h) * N_TOK + i0) * N_TOK;
  const int i_row = i0 + cl;
  const int ri = i_row >> 5, ci = i_row & 31;
  const float* bt = bias2e + (h << 12);
  const int C = (ri - (wv >> 1)) * 63 + ci - ((wv & 1) * 16 + rg * 4) + 1984;
  float s1 = 0.f;
  #pragma unroll
  for (int c = 0; c < 2; ++c) {
    #pragma unroll
    for (int tj8 = 0; tj8 < 8; ++tj8) {
      int tj = c * 8 + tj8;
      #pragma unroll
      for (int r = 0; r < 4; ++r)
        stage[(tj8 * 64 + wv * 16 + rg * 4 + r) * 17 + cl] = sc[tj][r] * iv0;
    }
    lds_barrier();                                         // barrier 3/5
    #pragma unroll
    for (int k = 0; k < 4; ++k) {
      int row = wv * 4 + k;
      #pragma unroll
      for (int e = 0; e < 8; ++e) {
        float v = stage[(e * 64 + lane) * 17 + row];
        out2[o2base + (size_t)row * N_TOK + c * 512 + e * 64 + lane] = v;
      }
    }
    if (userpe) {   // bias gathers overlap the store drain; mult while stores fly
      #pragma unroll
      for (int tj8 = 0; tj8 < 8; ++tj8) {
        int tj = c * 8 + tj8;
        f32x4u bv = *(const f32x4u*)&bt[C - tj * 126 - 3]; // [r3, r2, r1, r0]
        float v0 = sc[tj][0] * bv[3];
        float v1 = sc[tj][1] * bv[2];
        float v2 = sc[tj][2] * bv[1];
        float v3 = sc[tj][3] * bv[0];
        sc[tj][0] = v0; sc[tj][1] = v1; sc[tj][2] = v2; sc[tj][3] = v3;
        s1 += (v0 + v1) + (v2 + v3);
      }
    }
    lds_barrier();                                         // barrier 4/6
  }

  float iv1;
  if (userpe) {
    s1 += __shfl_xor(s1, 16);
    s1 += __shfl_xor(s1, 32);
    if (lane < 16) red0[wv][lane] = s1;
    lds_barrier();                                         // barrier 7
    iv1 = 1.f / (red0[0][cl] + red0[1][cl] + red0[2][cl] + red0[3][cl]);
  } else {
    iv1 = iv0;
  }

  // ---- chunked P pack + PV (wave-private half-passes), V ping-pong prefetch ----
  unsigned short* P_c = (unsigned short*)arena;    // [16 i][4 wv x 130] pitch 520
  const short* vf = Vfrag + (((size_t)bh * 8) * 16 + wv * 4) * 512 + lane * 8;
  f32x4 oacc[4];
  #pragma unroll
  for (int dt = 0; dt < 4; ++dt) oacc[dt] = (f32x4){0.f, 0.f, 0.f, 0.f};
  bf16x8 vc0 = *(const bf16x8*)&vf[0];
  bf16x8 vc1 = *(const bf16x8*)&vf[512];
  bf16x8 vc2 = *(const bf16x8*)&vf[1024];
  bf16x8 vc3 = *(const bf16x8*)&vf[1536];
  #pragma unroll
  for (int ch = 0; ch < 2; ++ch) {
    #pragma unroll
    for (int tj8 = 0; tj8 < 8; ++tj8) {
      int tj = ch * 8 + tj8;
      unsigned u0 = pack2bf(sc[tj][0] * iv1, sc[tj][1] * iv1);
      unsigned u1 = pack2bf(sc[tj][2] * iv1, sc[tj][3] * iv1);
      uint2 uu; uu.x = u0; uu.y = u1;
      *(uint2*)&P_c[cl * 520 + wv * 130 + tj8 * 16 + rg * 4] = uu;
    }
    #pragma unroll
    for (int w4 = 0; w4 < 4; ++w4) {
      int w = ch * 4 + w4;
      bf16x8 vn0, vn1, vn2, vn3;
      if (w < 7) {
        vn0 = *(const bf16x8*)&vf[(w + 1) * 8192];
        vn1 = *(const bf16x8*)&vf[(w + 1) * 8192 + 512];
        vn2 = *(const bf16x8*)&vf[(w + 1) * 8192 + 1024];
        vn3 = *(const bf16x8*)&vf[(w + 1) * 8192 + 1536];
      }
      int tjr = (2 * w + (rg >> 1)) & 7;
      bf16x8 pb = *(const bf16x8*)&P_c[cl * 520 + wv * 130 + tjr * 16 + (rg & 1) * 8];
      oacc[0] = MFMA16(vc0, pb, oacc[0], 0, 0, 0);
      oacc[1] = MFMA16(vc1, pb, oacc[1], 0, 0, 0);
      oacc[2] = MFMA16(vc2, pb, oacc[2], 0, 0, 0);
      oacc[3] = MFMA16(vc3, pb, oacc[3], 0, 0, 0);
      vc0 = vn0; vc1 = vn1; vc2 = vn2; vc3 = vn3;
    }
  }

  // ---- cross-wave O reduction ----
  lds_barrier();                                           // barrier 8 (P_c reads done)
  float* buf = (float*)arena;                       // [4][16][65]
  #pragma unroll
  for (int dt = 0; dt < 4; ++dt)
    #pragma unroll
    for (int r = 0; r < 4; ++r)
      buf[wv * 1040 + cl * 65 + dt * 16 + rg * 4 + r] = oacc[dt][r];
  lds_barrier();

  const int i_ = t >> 4, dq = t & 15;
  float o[4];
  #pragma unroll
  for (int k = 0; k < 4; ++k) {
    int d = dq * 4 + k;
    o[k] = buf[0 * 1040 + i_ * 65 + d] + buf[1 * 1040 + i_ * 65 + d]
         + buf[2 * 1040 + i_ * 65 + d] + buf[3 * 1040 + i_ * 65 + d];
  }
  short4 os;
  os.x = f2bf(o[0]); os.y = f2bf(o[1]); os.z = f2bf(o[2]); os.w = f2bf(o[3]);
  *(short4*)&Qb[(rowbase + i0 + i_) * 512 + h * DIM_HEAD + dq * 4] = os;  // O in-place
}

extern "C" void kernel_launch(void* const* d_in, const int* in_sizes, int n_in,
                              void* d_out, int out_size, void* d_ws, size_t ws_size,
                              hipStream_t stream) {
  const float* x    = (const float*)d_in[0];
  const float* Wqkv = (const float*)d_in[1];
  const float* Wout = (const float*)d_in[2];
  const float* bout = (const float*)d_in[3];
  const float* rel  = (const float*)d_in[4];
  const float* sita = (const float*)d_in[5];
  const int*   rpe  = (const int*)d_in[6];

  char* ws = (char*)d_ws;
  short* xb     = (short*)(ws);                 //  8 MB  x bf16
  short* WqT    = (short*)(ws + 8388608);       //  1.5MB W_qkv^T
  short* WoT    = (short*)(ws + 9961472);       //  0.5MB W_out^T
  short* Qbuf   = (short*)(ws + 10485760);      //  8 MB  Q [8192][512]; becomes O in-place
  short* Kfrag  = (short*)(ws + 18874368);      //  8 MB  K fragments
  float* bias2e = (float*)(ws + 27262976);      // 128 KB exp'd fused bias [8][4096]
  short* Vfrag  = (short*)(ws + 35651584);      //  8 MB  V fragments

  float* out1 = (float*)d_out;
  float* out2 = out1 + (size_t)BATCH * N_TOK * DIMM;

  hipLaunchKernelGGL(prep_kernel, dim3(4480), dim3(256), 0, stream,
                     x, xb, Wqkv, WqT, Wout, WoT, rel, sita, bias2e);
  hipLaunchKernelGGL((gemm_kernel<1>), dim3(12, 64), dim3(256), 0, stream,
                     xb, WqT, (void*)nullptr, (const float*)nullptr,
                     Qbuf, Kfrag, Vfrag, 8192, 1536, 512, 512);
  hipLaunchKernelGGL(attn_kernel, dim3(4096), dim3(256), 0, stream,
                     Qbuf, Kfrag, Vfrag, bias2e, rpe, out2);
  hipLaunchKernelGGL((gemm_kernel<0>), dim3(4, 64), dim3(256), 0, stream,
                     Qbuf, WoT, d_out, bout,
                     (short*)nullptr, (short*)nullptr, (short*)nullptr, 8192, 512, 512, 512);
}